// Round 1
// baseline (9905.006 us; speedup 1.0000x reference)
//
#include <hip/hip_runtime.h>
#include <hip/hip_bf16.h>

#define B_   256
#define T_   64
#define OBS_ 1024
#define ACT_ 6
#define STO_ 32
#define HID_ 1024
#define DET_ 1024

using bf16 = __bf16;
typedef __attribute__((ext_vector_type(8))) __bf16 bf16x8;
typedef __attribute__((ext_vector_type(4))) float f32x4;

// ---------------- fp32 -> bf16 conversion ----------------
__global__ void k_cvt(const float* __restrict__ s, bf16* __restrict__ d, int n) {
  int i = blockIdx.x * 256 + threadIdx.x;
  if (i < n) d[i] = (bf16)s[i];
}

// x1 for t=0: z0=0, a0=0 -> relu(in_b1) broadcast over batch
__global__ void k_x1init(const float* __restrict__ b1, bf16* __restrict__ x1) {
  int i = blockIdx.x * 256 + threadIdx.x;   // B_*HID_ threads
  x1[i] = (bf16)fmaxf(b1[i & (HID_ - 1)], 0.f);
}

// ---------------- MFMA GEMM: out[m,n] = act(sum_k A[m,k]*W[n,k] + b[n]) ----------------
// A: bf16 [256,K1] (+ optional second segment A2 [256,K-K1]); W: bf16 [N,K] row-major.
// Block = 256 thr = 4 waves; block tile [64 m x 64 n]; wave w: rows m0+16w..+15, all 64 cols.
struct GArg {
  const bf16* A;     // [256, K1]
  const bf16* A2;    // [256, K-K1] or nullptr
  const bf16* W;     // [N, K]
  const float* bias; // [N] or nullptr
  bf16* outB;        // [256, N] or nullptr
  float* outF;       // [256, N] or nullptr
  int K1, K, relu;
};

__global__ __launch_bounds__(256) void k_gemm(GArg g0, GArg g1, int N) {
  GArg g = blockIdx.z ? g1 : g0;
  const int tid  = threadIdx.x;
  const int lane = tid & 63;
  const int wv   = tid >> 6;
  const int l15  = lane & 15;
  const int kq   = (lane >> 4) << 3;          // 0,8,16,24
  const int n0   = blockIdx.x * 64;
  const int m0   = blockIdx.y * 64 + wv * 16;
  const int K = g.K, K1 = g.K1;
  const int K2 = K - K1;

  f32x4 acc0 = {0.f,0.f,0.f,0.f};
  f32x4 acc1 = acc0, acc2 = acc0, acc3 = acc0;

  // A fragment: lane l, elem j -> A[m0 + (l&15)][k0 + (l>>4)*8 + j]  (contiguous 16B)
  // B fragment: lane l, elem j -> B[k0+(l>>4)*8+j][n0+(l&15)] = W[n0+(l&15)][k0+(l>>4)*8+j]
  const bf16* __restrict__ a1p = g.A + (size_t)(m0 + l15) * K1 + kq;
  const bf16* __restrict__ w0p = g.W + (size_t)(n0 + l15) * K  + kq;

  #pragma unroll 2
  for (int k0 = 0; k0 < K1; k0 += 32) {
    bf16x8 af = *(const bf16x8*)(a1p + k0);
    const bf16* wp = w0p + k0;
    acc0 = __builtin_amdgcn_mfma_f32_16x16x32_bf16(af, *(const bf16x8*)(wp                ), acc0, 0,0,0);
    acc1 = __builtin_amdgcn_mfma_f32_16x16x32_bf16(af, *(const bf16x8*)(wp + (size_t)16*K), acc1, 0,0,0);
    acc2 = __builtin_amdgcn_mfma_f32_16x16x32_bf16(af, *(const bf16x8*)(wp + (size_t)32*K), acc2, 0,0,0);
    acc3 = __builtin_amdgcn_mfma_f32_16x16x32_bf16(af, *(const bf16x8*)(wp + (size_t)48*K), acc3, 0,0,0);
  }
  if (g.A2) {
    const bf16* __restrict__ a2p = g.A2 + (size_t)(m0 + l15) * K2 + kq;
    #pragma unroll 2
    for (int k0 = K1; k0 < K; k0 += 32) {
      bf16x8 af = *(const bf16x8*)(a2p + (k0 - K1));
      const bf16* wp = w0p + k0;
      acc0 = __builtin_amdgcn_mfma_f32_16x16x32_bf16(af, *(const bf16x8*)(wp                ), acc0, 0,0,0);
      acc1 = __builtin_amdgcn_mfma_f32_16x16x32_bf16(af, *(const bf16x8*)(wp + (size_t)16*K), acc1, 0,0,0);
      acc2 = __builtin_amdgcn_mfma_f32_16x16x32_bf16(af, *(const bf16x8*)(wp + (size_t)32*K), acc2, 0,0,0);
      acc3 = __builtin_amdgcn_mfma_f32_16x16x32_bf16(af, *(const bf16x8*)(wp + (size_t)48*K), acc3, 0,0,0);
    }
  }

  // D: lane l, reg r -> D[m0 + (l>>4)*4 + r][n0 + 16*t + (l&15)]  (m89/m91-verified)
  const int mr = m0 + ((lane >> 4) << 2);
  f32x4 accs[4] = {acc0, acc1, acc2, acc3};
  #pragma unroll
  for (int t = 0; t < 4; t++) {
    const int n = n0 + t * 16 + l15;
    const float bv = g.bias ? g.bias[n] : 0.f;
    #pragma unroll
    for (int r = 0; r < 4; r++) {
      float v = accs[t][r] + bv;
      if (g.relu) v = fmaxf(v, 0.f);
      const size_t off = (size_t)(mr + r) * N + n;
      if (g.outB) g.outB[off] = (bf16)v;
      if (g.outF) g.outF[off] = v;
    }
  }
}

// ---------------- GRU elementwise + feat h-part + obs_t bf16 conversion ----------------
__global__ void k_gru(const float* __restrict__ gi, const float* __restrict__ gh,
                      float* __restrict__ hf, bf16* __restrict__ hb,
                      const float* __restrict__ obs, bf16* __restrict__ obsb,
                      float* __restrict__ feat, int t) {
  const int idx = blockIdx.x * 256 + threadIdx.x;   // < B_*DET_
  const int m = idx >> 10, i = idx & 1023;
  const size_t base = (size_t)m * 3072;
  float r  = gi[base + i]        + gh[base + i];
  float u  = gi[base + 1024 + i] + gh[base + 1024 + i];
  float nn = gi[base + 2048 + i];
  float hn = gh[base + 2048 + i];
  r = 1.f / (1.f + __expf(-r));
  u = 1.f / (1.f + __expf(-u));
  float n = tanhf(nn + r * hn);
  float h = hf[idx];
  float hnew = (1.f - u) * n + u * h;
  hf[idx] = hnew;
  hb[idx] = (bf16)hnew;
  feat[((size_t)m * T_ + t) * 1056 + i] = hnew;
  obsb[idx] = (bf16)obs[((size_t)m * T_ + t) * OBS_ + i];
}

// ---------------- heads finish + z + feat z-part + next-step x1 ----------------
__global__ __launch_bounds__(256) void k_fin(
    const float* __restrict__ rawp, const float* __restrict__ rawq,   // [256,64] pre-bias
    const float* __restrict__ pr_mb, const float* __restrict__ pr_sb,
    const float* __restrict__ po_mb, const float* __restrict__ po_sb,
    const float* __restrict__ eps_post, const float* __restrict__ actions,
    const float* __restrict__ in_w1, const float* __restrict__ in_b1,
    float* __restrict__ pm, float* __restrict__ ps,
    float* __restrict__ qm, float* __restrict__ qs,
    float* __restrict__ feat, bf16* __restrict__ x1b, int t) {
  const int m = blockIdx.x, tid = threadIdx.x;
  __shared__ float qml[STO_], qsl[STO_], zl[STO_], al[ACT_];
  if (tid < 128) {
    const int hsel = tid >> 5, j = tid & 31;
    const size_t o = ((size_t)m * T_ + t) * STO_ + j;
    if (hsel == 0) {
      pm[o] = rawp[m * 64 + j] + pr_mb[j];
    } else if (hsel == 1) {
      float v = rawp[m * 64 + 32 + j] + pr_sb[j];
      ps[o] = __expf(fminf(fmaxf(v, -5.f), 2.f));
    } else if (hsel == 2) {
      float v = rawq[m * 64 + j] + po_mb[j];
      qml[j] = v; qm[o] = v;
    } else {
      float v = rawq[m * 64 + 32 + j] + po_sb[j];
      v = __expf(fminf(fmaxf(v, -5.f), 2.f));
      qsl[j] = v; qs[o] = v;
    }
  }
  if (tid < ACT_) al[tid] = actions[((size_t)m * T_ + t) * ACT_ + tid];
  __syncthreads();
  if (tid < STO_) {
    float z = qml[tid] + qsl[tid] * eps_post[((size_t)m * T_ + t) * STO_ + tid];
    zl[tid] = z;
    feat[((size_t)m * T_ + t) * 1056 + 1024 + tid] = z;
  }
  __syncthreads();
  // x1 for step t+1: relu([z, a_t] @ in_w1^T + in_b1), K=38, fp32
  #pragma unroll
  for (int q = 0; q < 4; q++) {
    const int n = tid * 4 + q;
    const float* w = in_w1 + n * 38;
    float acc = in_b1[n];
    #pragma unroll
    for (int k = 0; k < STO_; k++) acc = fmaf(zl[k], w[k], acc);
    #pragma unroll
    for (int k = 0; k < ACT_; k++) acc = fmaf(al[k], w[32 + k], acc);
    x1b[(size_t)m * HID_ + n] = (bf16)fmaxf(acc, 0.f);
  }
}

extern "C" void kernel_launch(void* const* d_in, const int* in_sizes, int n_in,
                              void* d_out, int out_size, void* d_ws, size_t ws_size,
                              hipStream_t stream) {
  (void)in_sizes; (void)n_in; (void)out_size; (void)ws_size;
  const float* obs      = (const float*)d_in[0];
  const float* actions  = (const float*)d_in[1];
  const float* eps_post = (const float*)d_in[3];   // eps_prior (d_in[2]) is unused by the math
  const float* in_w1 = (const float*)d_in[4];
  const float* in_b1 = (const float*)d_in[5];
  const float* in_w2 = (const float*)d_in[6];
  const float* in_b2 = (const float*)d_in[7];
  const float* gru_wih = (const float*)d_in[8];
  const float* gru_whh = (const float*)d_in[9];
  const float* gru_bih = (const float*)d_in[10];
  const float* gru_bhh = (const float*)d_in[11];
  const float* pr_w1 = (const float*)d_in[12];
  const float* pr_b1 = (const float*)d_in[13];
  const float* pr_w2 = (const float*)d_in[14];
  const float* pr_b2 = (const float*)d_in[15];
  const float* pr_mw = (const float*)d_in[16];
  const float* pr_mb = (const float*)d_in[17];
  const float* pr_sw = (const float*)d_in[18];
  const float* pr_sb = (const float*)d_in[19];
  const float* po_w1 = (const float*)d_in[20];
  const float* po_b1 = (const float*)d_in[21];
  const float* po_w2 = (const float*)d_in[22];
  const float* po_b2 = (const float*)d_in[23];
  const float* po_mw = (const float*)d_in[24];
  const float* po_mb = (const float*)d_in[25];
  const float* po_sw = (const float*)d_in[26];
  const float* po_sb = (const float*)d_in[27];

  float* feat = (float*)d_out;
  float* pm = feat + (size_t)B_ * T_ * 1056;
  float* ps = pm + (size_t)B_ * T_ * STO_;
  float* qm = ps + (size_t)B_ * T_ * STO_;
  float* qs = qm + (size_t)B_ * T_ * STO_;

  // ---- workspace carve (~33.5 MB) ----
  char* wp_ = (char*)d_ws;
  auto carve = [&](size_t bytes) -> void* {
    void* r = (void*)wp_;
    wp_ += (bytes + 255) & ~(size_t)255;
    return r;
  };
  bf16* w_in2b = (bf16*)carve((size_t)HID_ * HID_ * 2);
  bf16* w_wihb = (bf16*)carve((size_t)3 * DET_ * HID_ * 2);
  bf16* w_whhb = (bf16*)carve((size_t)3 * DET_ * DET_ * 2);
  bf16* w_pr1b = (bf16*)carve((size_t)HID_ * DET_ * 2);
  bf16* w_pr2b = (bf16*)carve((size_t)HID_ * HID_ * 2);
  bf16* w_po1b = (bf16*)carve((size_t)HID_ * (DET_ + OBS_) * 2);
  bf16* w_po2b = (bf16*)carve((size_t)HID_ * HID_ * 2);
  bf16* w_phb  = (bf16*)carve((size_t)64 * HID_ * 2);   // [pr_mw; pr_sw]
  bf16* w_qhb  = (bf16*)carve((size_t)64 * HID_ * 2);   // [po_mw; po_sw]
  bf16* x1b  = (bf16*)carve((size_t)B_ * HID_ * 2);
  bf16* x2b  = (bf16*)carve((size_t)B_ * HID_ * 2);
  bf16* hb   = (bf16*)carve((size_t)B_ * DET_ * 2);
  float* hf  = (float*)carve((size_t)B_ * DET_ * 4);
  float* gi  = (float*)carve((size_t)B_ * 3 * DET_ * 4);
  float* gh  = (float*)carve((size_t)B_ * 3 * DET_ * 4);
  bf16* p1b  = (bf16*)carve((size_t)B_ * HID_ * 2);
  bf16* q1b  = (bf16*)carve((size_t)B_ * HID_ * 2);
  bf16* p2b  = (bf16*)carve((size_t)B_ * HID_ * 2);
  bf16* q2b  = (bf16*)carve((size_t)B_ * HID_ * 2);
  bf16* obsb = (bf16*)carve((size_t)B_ * OBS_ * 2);
  float* rawp = (float*)carve((size_t)B_ * 64 * 4);
  float* rawq = (float*)carve((size_t)B_ * 64 * 4);

  // ---- one-time per-launch prep ----
  auto cvt = [&](const float* s, bf16* d, size_t n) {
    k_cvt<<<dim3((unsigned)((n + 255) / 256)), dim3(256), 0, stream>>>(s, d, (int)n);
  };
  cvt(in_w2,   w_in2b, (size_t)HID_ * HID_);
  cvt(gru_wih, w_wihb, (size_t)3 * DET_ * HID_);
  cvt(gru_whh, w_whhb, (size_t)3 * DET_ * DET_);
  cvt(pr_w1,   w_pr1b, (size_t)HID_ * DET_);
  cvt(pr_w2,   w_pr2b, (size_t)HID_ * HID_);
  cvt(po_w1,   w_po1b, (size_t)HID_ * (DET_ + OBS_));
  cvt(po_w2,   w_po2b, (size_t)HID_ * HID_);
  cvt(pr_mw,   w_phb,                       (size_t)STO_ * HID_);
  cvt(pr_sw,   w_phb + (size_t)STO_ * HID_, (size_t)STO_ * HID_);
  cvt(po_mw,   w_qhb,                       (size_t)STO_ * HID_);
  cvt(po_sw,   w_qhb + (size_t)STO_ * HID_, (size_t)STO_ * HID_);
  hipMemsetAsync(hf, 0, (size_t)B_ * DET_ * 4, stream);
  hipMemsetAsync(hb, 0, (size_t)B_ * DET_ * 2, stream);
  k_x1init<<<dim3(B_ * HID_ / 256), dim3(256), 0, stream>>>(in_b1, x1b);

  // ---- rollout ----
  for (int t = 0; t < T_; t++) {
    // x2 = relu(x1 @ in_w2^T + in_b2)
    GArg gin2 = { x1b, nullptr, w_in2b, in_b2, x2b, nullptr, HID_, HID_, 1 };
    k_gemm<<<dim3(HID_ / 64, 4, 1), dim3(256), 0, stream>>>(gin2, gin2, HID_);
    // gi = x2 @ wih^T + bih ; gh = h @ whh^T + bhh
    GArg ggi = { x2b, nullptr, w_wihb, gru_bih, nullptr, gi, HID_, HID_, 0 };
    GArg ggh = { hb,  nullptr, w_whhb, gru_bhh, nullptr, gh, DET_, DET_, 0 };
    k_gemm<<<dim3(3 * DET_ / 64, 4, 2), dim3(256), 0, stream>>>(ggi, ggh, 3 * DET_);
    // GRU gates -> h_new; feat[:, t, :1024]; obs_t -> bf16
    k_gru<<<dim3(B_ * DET_ / 256), dim3(256), 0, stream>>>(gi, gh, hf, hb, obs, obsb, feat, t);
    // pr1 = relu(h @ pr_w1^T) ; po1 = relu([h, obs_t] @ po_w1^T)
    GArg gpr1 = { hb, nullptr, w_pr1b, pr_b1, p1b, nullptr, DET_, DET_, 1 };
    GArg gpo1 = { hb, obsb,    w_po1b, po_b1, q1b, nullptr, DET_, DET_ + OBS_, 1 };
    k_gemm<<<dim3(HID_ / 64, 4, 2), dim3(256), 0, stream>>>(gpr1, gpo1, HID_);
    // pr2 / po2
    GArg gpr2 = { p1b, nullptr, w_pr2b, pr_b2, p2b, nullptr, HID_, HID_, 1 };
    GArg gpo2 = { q1b, nullptr, w_po2b, po_b2, q2b, nullptr, HID_, HID_, 1 };
    k_gemm<<<dim3(HID_ / 64, 4, 2), dim3(256), 0, stream>>>(gpr2, gpo2, HID_);
    // heads (pre-bias): rawp = p2 @ [pr_mw;pr_sw]^T ; rawq = q2 @ [po_mw;po_sw]^T
    GArg ghp = { p2b, nullptr, w_phb, nullptr, nullptr, rawp, HID_, HID_, 0 };
    GArg ghq = { q2b, nullptr, w_qhb, nullptr, nullptr, rawq, HID_, HID_, 0 };
    k_gemm<<<dim3(1, 4, 2), dim3(256), 0, stream>>>(ghp, ghq, 64);
    // finish: stats, z, feat z-part, next x1
    k_fin<<<dim3(B_), dim3(256), 0, stream>>>(rawp, rawq, pr_mb, pr_sb, po_mb, po_sb,
                                              eps_post, actions, in_w1, in_b1,
                                              pm, ps, qm, qs, feat, x1b, t);
  }
}